// Round 10
// baseline (799.075 us; speedup 1.0000x reference)
//
#include <hip/hip_runtime.h>
#include <hip/hip_bf16.h>

// ---------------------------------------------------------------------------
// lora_cross_attention, round 10: fp16 MFMA GEMM, register-blocked 128x128
// per wave (MFMA:ds_read = 4.0 -- the round-2 anomaly says ratio is the
// binding variable; all ratio<=2.67 fp16 variants pinned at ~700 TF = LDS
// read ceiling).
// conv(img,text,W* -> fp16) -> q = img x Wq^T -> k,v (fused, grid.z)
// -> fused attention (fp16, O in-place over q) -> out = O x Wo^T (fp32).
// GEMM: 256x256 tile, BK=32, 4 waves (2x2, each 128x128, acc 8x8 frags =
// 256 VGPR), TRIPLE-buffered 96 KB LDS, stage distance 2, per-iter
// vmcnt(8)+barrier certification (round-7/8-proven), compiler lgkm inside.
// ---------------------------------------------------------------------------

typedef unsigned short u16;
typedef _Float16 f16x8 __attribute__((ext_vector_type(8)));
typedef __attribute__((ext_vector_type(8))) short s16x8;
typedef __attribute__((ext_vector_type(4))) float f32x4;
typedef __attribute__((ext_vector_type(4))) short s16x4;

#define MFMAH(a, b, c) __builtin_amdgcn_mfma_f32_16x16x32_f16(a, b, c, 0, 0, 0)

__device__ __forceinline__ u16 f2h(float x) {
    _Float16 h = (_Float16)x;              // v_cvt_f16_f32, RNE
    return __builtin_bit_cast(u16, h);
}

__device__ __forceinline__ void gload16(const u16* g, const u16* l) {
    __builtin_amdgcn_global_load_lds(
        (const __attribute__((address_space(1))) unsigned int*)g,
        (__attribute__((address_space(3))) unsigned int*)l, 16, 0, 0);
}

// row-hash for the 16B-chunk swizzle — (r>>1)&3 measured 0 bank conflicts
// (round 4 PMC); (r&3)^((r>>2)&3) measured 1.4e7 (rounds 3/7).
__device__ __forceinline__ int rh(int r) { return (r >> 1) & 3; }

// ---------------------------------------------------------------------------
// fp32 -> fp16 conversion
// ---------------------------------------------------------------------------
__global__ void conv_h(const float* __restrict__ x, u16* __restrict__ h, int n8) {
    const int i = blockIdx.x * 256 + threadIdx.x;
    if (i >= n8) return;
    const f32x4 a = ((const f32x4*)x)[2 * i];
    const f32x4 b = ((const f32x4*)x)[2 * i + 1];
    u16 o[8];
#pragma unroll
    for (int j = 0; j < 4; ++j) { o[j] = f2h(a[j]); o[4 + j] = f2h(b[j]); }
    *(s16x8*)&h[(size_t)i << 3] = *(s16x8*)o;
}

struct Conv5Args {
    const float* x[5];
    u16* h[5];
    int n8[5];
};

__global__ void conv_h5(Conv5Args A) {
    const int z = blockIdx.y;
    const int i = blockIdx.x * 256 + threadIdx.x;
    if (i >= A.n8[z]) return;
    const float* x = A.x[z];
    const f32x4 a = ((const f32x4*)x)[2 * i];
    const f32x4 b = ((const f32x4*)x)[2 * i + 1];
    u16 o[8];
#pragma unroll
    for (int j = 0; j < 4; ++j) { o[j] = f2h(a[j]); o[4 + j] = f2h(b[j]); }
    *(s16x8*)&A.h[z][(size_t)i << 3] = *(s16x8*)o;
}

// ---------------------------------------------------------------------------
// C[M,N] = A[M,K] x B[N,K]^T + bias, fp16 in, fp32/fp16 out.
// 256x256 tile, BK=32, 256 threads (4 waves 2x2, each 128x128 output).
// LDS: 3 buffers x 32 KB (buf i at u16 offset i*16384; A [256][32] @+0,
// B [256][32] @+8192). Row r, 16B-slot s holds k-chunk s ^ rh(r).
// Per K-tile: stage tile t+2 (8 gloads) | 8 A ds_read | 8x{B ds_read +
// 8 MFMA} (compiler lgkm) | vmcnt(8) | barrier.  Ratio: 64 MFMA/16 reads.
// grid.z selects (B,bias,C) set 0/1 (fuses k and v projections).
// ---------------------------------------------------------------------------
template <int OUTF32>
__global__ __launch_bounds__(256, 1) void gemm_h_nt(
    const u16* __restrict__ A,
    const u16* __restrict__ B0, const float* __restrict__ bias0, void* __restrict__ C0,
    const u16* __restrict__ B1, const float* __restrict__ bias1, void* __restrict__ C1,
    int M, int N, int K, int nby) {
    __shared__ u16 lds[49152];   // 96 KB = 3 x 32 KB buffers

    const u16* B = B0; const float* bias = bias0; void* Cout = C0;
    if (blockIdx.z) { B = B1; bias = bias1; Cout = C1; }

    // XCD-bijective block swizzle (m204); consecutive wgid share the A panel.
    const int nwg = gridDim.x;
    const int q8 = nwg >> 3, r8 = nwg & 7;
    const int xcd = blockIdx.x & 7, loc = blockIdx.x >> 3;
    const int wgid = (xcd < r8 ? xcd * (q8 + 1) : r8 * (q8 + 1) + (xcd - r8) * q8) + loc;
    const int bx = wgid / nby, by = wgid - bx * nby;
    const int row0 = bx * 256, col0 = by * 256;

    const int t = threadIdx.x, lane = t & 63, w = t >> 6;
    const int wm = w >> 1, wn = w & 1;
    const int l15 = lane & 15, lhi = lane >> 4;

    // staging: per tile, A = 1024 16B-chunks (256 rows x 4 slots); thread t
    // owns chunks t, 256+t, 512+t, 768+t. Same for B. k-chunk = slot^rh(row).
    const u16* gpA[4]; const u16* gpB[4];
    int lofA[4], lofB[4];
#pragma unroll
    for (int it = 0; it < 4; ++it) {
        const int ci = it * 256 + t;
        const int row = ci >> 2, slot = ci & 3;
        const int gs = slot ^ rh(row);
        int ar = row0 + row; if (ar > M - 1) ar = M - 1;   // tail clamp (stores guarded)
        gpA[it] = A + (size_t)ar * K + (gs << 3);
        gpB[it] = B + (size_t)(col0 + row) * K + (gs << 3);
        lofA[it] = ci * 8;
        lofB[it] = 8192 + ci * 8;
    }

    // fragment read offsets: frag row = mult-of-16 + l15 -> rh depends on l15.
    const int ss = rh(l15);
    int aof[8], bof[8];
#pragma unroll
    for (int i = 0; i < 8; ++i) {
        const int ar = wm * 128 + i * 16 + l15;
        aof[i] = ar * 32 + ((lhi ^ ss) << 3);
        const int br = wn * 128 + i * 16 + l15;
        bof[i] = 8192 + br * 32 + ((lhi ^ ss) << 3);
    }

    f32x4 acc[8][8] = {};
    const int NT = K >> 5;   // K=1536 -> 48 (>= 3 required)

#define SBAR0() __builtin_amdgcn_sched_barrier(0)

    // prologue: stage tiles 0,1 into bufs 0,1 (8 gloads each, in order)
#pragma unroll
    for (int p = 0; p < 2; ++p) {
        const size_t kp = (size_t)p << 5;
        u16* lb = lds + (p << 14);
#pragma unroll
        for (int it = 0; it < 4; ++it) {
            gload16(gpA[it] + kp, lb + lofA[it]);
            gload16(gpB[it] + kp, lb + lofB[it]);
        }
    }
    // certify tile 0 for ALL waves: own vmcnt then barrier
    asm volatile("s_waitcnt vmcnt(8)" ::: "memory");
    SBAR0(); __builtin_amdgcn_s_barrier(); SBAR0();

    int cur = 0;                  // buffer holding tile tt
    for (int tt = 0; tt < NT; ++tt) {
        const int cb = cur << 14;
        int stg = cur + 2; if (stg >= 3) stg -= 3;     // buffer for tile tt+2
        u16* lsb = lds + (stg << 14);
        const int tx = (tt + 2 < NT) ? tt + 2 : tt + 2 - NT;  // wrap: vmcnt uniform
        const size_t kn = (size_t)tx << 5;

        // stage tile t+2 first (oldest VMEM ops of this iteration)
#pragma unroll
        for (int it = 0; it < 4; ++it) {
            gload16(gpA[it] + kn, lsb + lofA[it]);
            gload16(gpB[it] + kn, lsb + lofB[it]);
        }

        // A fragments (8 reads), then per-column: B read + 8 MFMA
        f16x8 a[8];
#pragma unroll
        for (int mf = 0; mf < 8; ++mf) a[mf] = *(const f16x8*)&lds[cb + aof[mf]];
#pragma unroll
        for (int nf = 0; nf < 8; ++nf) {
            const f16x8 bfr = *(const f16x8*)&lds[cb + bof[nf]];
#pragma unroll
            for (int mf = 0; mf < 8; ++mf)
                acc[mf][nf] = MFMAH(a[mf], bfr, acc[mf][nf]);
        }

        // gate tile t+1 (own loads: oldest-beyond-8 = iter t-1's, i.e. tile
        // t+1, retired), globalized by the barrier; also certifies that all
        // waves finished reading buf cur before it gets restaged next iter+1.
        asm volatile("s_waitcnt vmcnt(8)" ::: "memory");
        SBAR0(); __builtin_amdgcn_s_barrier(); SBAR0();

        cur = cur + 1; if (cur == 3) cur = 0;
    }
    asm volatile("s_waitcnt vmcnt(0)" ::: "memory");

    // epilogue: +bias, store (C/D: col=lane&15, row=lhi*4+reg)
#pragma unroll
    for (int nf = 0; nf < 8; ++nf) {
        const int col = col0 + wn * 128 + nf * 16 + l15;
        const float bs = bias[col];
#pragma unroll
        for (int mf = 0; mf < 8; ++mf) {
            const int row = row0 + wm * 128 + mf * 16 + (lhi << 2);
#pragma unroll
            for (int r = 0; r < 4; ++r) {
                if (row + r < M) {
                    const float v = acc[mf][nf][r] + bs;
                    if (OUTF32) ((float*)Cout)[(size_t)(row + r) * N + col] = v;
                    else        ((u16*)Cout)[(size_t)(row + r) * N + col] = f2h(v);
                }
            }
        }
    }
#undef SBAR0
}

// ---------------------------------------------------------------------------
// Fused attention, fp16 in/out. One block per (qtile=64,h,b), 4 waves x 16
// q-rows. Sk=77 one-shot. O written IN-PLACE over q (each wave reads exactly
// the rows+head-slice it later writes; Q register-resident first).
// ---------------------------------------------------------------------------
#define ALDK 200
#define ALDP 104

__global__ void attn_fused(const u16* __restrict__ qbuf, const u16* __restrict__ kbuf,
                           const u16* __restrict__ vbuf, u16* __restrict__ obuf) {
    __shared__ u16 Ks[80 * ALDK];   // 32000 B
    __shared__ u16 Pls[64 * ALDP];  // 13312 B
    __shared__ u16 Vt[96 * ALDP];   // 19968 B (65280 total)

    const int t = threadIdx.x, lane = t & 63, w = t >> 6;
    const int qt = blockIdx.x, h = blockIdx.y, b = blockIdx.z;
    const int l15 = lane & 15, lhi = lane >> 4;

    // Q fragments straight from global fp16
    f16x8 qf[6];
    {
        const size_t qrow = (size_t)(b * 1024 + qt * 64 + w * 16 + l15);
        const u16* qp = qbuf + qrow * 1536 + h * 192 + (lhi << 3);
#pragma unroll
        for (int kt = 0; kt < 6; ++kt) qf[kt] = *(const f16x8*)(qp + kt * 32);
    }

    // stage K [80][192], rows >=77 zero
    for (int c = t; c < 80 * 24; c += 256) {
        const int s = c / 24, d8 = (c - s * 24) << 3;
        s16x8 val = {};
        if (s < 77) val = *(const s16x8*)&kbuf[(size_t)(b * 77 + s) * 1536 + h * 192 + d8];
        *(s16x8*)&Ks[s * ALDK + d8] = val;
    }
    // stage V^T half 0: d in [0,96); s fastest across lanes (conflict-free)
    for (int c = t; c < 96 * 12; c += 256) {
        const int s = c % 96, d8 = (c / 96) << 3;
        s16x8 val = {};
        if (s < 77) val = *(const s16x8*)&vbuf[(size_t)(b * 77 + s) * 1536 + h * 192 + d8];
#pragma unroll
        for (int j = 0; j < 8; ++j) Vt[(d8 + j) * ALDP + s] = (u16)val[j];
    }
    // zero P pad cols 80..95 (own rows)
    {
        const int row = w * 16 + l15;
        s16x4 z = {0, 0, 0, 0};
        *(s16x4*)&Pls[row * ALDP + 80 + (lhi << 2)] = z;
    }
    __syncthreads();

    // scores S[16 q-rows][80 k-cols] per wave
    f32x4 sacc[5] = {};
#pragma unroll
    for (int kt = 0; kt < 6; ++kt) {
#pragma unroll
        for (int nf = 0; nf < 5; ++nf) {
            f16x8 kf = *(const f16x8*)&Ks[(nf * 16 + l15) * ALDK + kt * 32 + (lhi << 3)];
            sacc[nf] = MFMAH(qf[kt], kf, sacc[nf]);
        }
    }

    // softmax per q-row (row = lhi*4 + r); P kept unnormalized
    float rps[4];
    const float scale = 0.07216878364870323f;   // 192^-0.5
#pragma unroll
    for (int r = 0; r < 4; ++r) {
        float m = -1e30f;
#pragma unroll
        for (int nf = 0; nf < 5; ++nf) {
            const int c = nf * 16 + l15;
            const float sv = sacc[nf][r] * scale;
            if (c < 77) m = fmaxf(m, sv);
        }
#pragma unroll
        for (int off = 1; off < 16; off <<= 1) m = fmaxf(m, __shfl_xor(m, off));
        float sum = 0.f;
#pragma unroll
        for (int nf = 0; nf < 5; ++nf) {
            const int c = nf * 16 + l15;
            const float p = (c < 77) ? __expf(sacc[nf][r] * scale - m) : 0.f;
            sacc[nf][r] = p;
            sum += p;
        }
#pragma unroll
        for (int off = 1; off < 16; off <<= 1) sum += __shfl_xor(sum, off);
        rps[r] = 1.0f / sum;   // sum >= 1
    }

    // write P (own 16 rows)
#pragma unroll
    for (int r = 0; r < 4; ++r)
#pragma unroll
        for (int nf = 0; nf < 5; ++nf)
            Pls[(w * 16 + (lhi << 2) + r) * ALDP + nf * 16 + l15] = f2h(sacc[nf][r]);
    __syncthreads();

    // P A-fragments
    f16x8 pa[3];
#pragma unroll
    for (int kt = 0; kt < 3; ++kt)
        pa[kt] = *(const f16x8*)&Pls[(w * 16 + l15) * ALDP + kt * 32 + (lhi << 3)];

    const size_t orow = (size_t)(b * 1024 + qt * 64 + w * 16 + (lhi << 2));

    // PV half 0 -> O[:, 0:96)
    {
        f32x4 oacc[6] = {};
#pragma unroll
        for (int kt = 0; kt < 3; ++kt)
#pragma unroll
            for (int nf = 0; nf < 6; ++nf) {
                f16x8 vf = *(const f16x8*)&Vt[(nf * 16 + l15) * ALDP + kt * 32 + (lhi << 3)];
                oacc[nf] = MFMAH(pa[kt], vf, oacc[nf]);
            }
#pragma unroll
        for (int nf = 0; nf < 6; ++nf) {
            const int col = h * 192 + nf * 16 + l15;
#pragma unroll
            for (int r = 0; r < 4; ++r)
                obuf[(orow + r) * 1536 + col] = f2h(oacc[nf][r] * rps[r]);
        }
    }
    __syncthreads();
    // stage V^T half 1: d in [96,192)
    for (int c = t; c < 96 * 12; c += 256) {
        const int s = c % 96, d8 = (c / 96) << 3;
        s16x8 val = {};
        if (s < 77) val = *(const s16x8*)&vbuf[(size_t)(b * 77 + s) * 1536 + h * 192 + 96 + d8];
#pragma unroll
        for (int j = 0; j < 8; ++j) Vt[(d8 + j) * ALDP + s] = (u16)val[j];
    }
    __syncthreads();
    // PV half 1 -> O[:, 96:192)
    {
        f32x4 oacc[6] = {};
#pragma unroll
        for (int kt = 0; kt < 3; ++kt)
#pragma unroll
            for (int nf = 0; nf < 6; ++nf) {
                f16x8 vf = *(const f16x8*)&Vt[(nf * 16 + l15) * ALDP + kt * 32 + (lhi << 3)];
                oacc[nf] = MFMAH(pa[kt], vf, oacc[nf]);
            }
#pragma unroll
        for (int nf = 0; nf < 6; ++nf) {
            const int col = h * 192 + 96 + nf * 16 + l15;
#pragma unroll
            for (int r = 0; r < 4; ++r)
                obuf[(orow + r) * 1536 + col] = f2h(oacc[nf][r] * rps[r]);
        }
    }
}

// ---------------------------------------------------------------------------
extern "C" void kernel_launch(void* const* d_in, const int* in_sizes, int n_in,
                              void* d_out, int out_size, void* d_ws, size_t ws_size,
                              hipStream_t stream) {
    const float* img  = (const float*)d_in[0];
    const float* text = (const float*)d_in[1];
    const float* Wq   = (const float*)d_in[2];
    const float* bq   = (const float*)d_in[3];
    const float* Wk   = (const float*)d_in[4];
    const float* bk   = (const float*)d_in[5];
    const float* Wv   = (const float*)d_in[6];
    const float* bv   = (const float*)d_in[7];
    const float* Wo   = (const float*)d_in[8];
    const float* bo   = (const float*)d_in[9];

    const size_t imgN = (size_t)32768 * 1536;
    const size_t txtN = (size_t)2464 * 1536;
    const size_t wN   = (size_t)1536 * 1536;

    // ws layout (~230 MB of fp16)
    u16* img_h = (u16*)d_ws;        // [imgN]
    u16* qb    = img_h + imgN;      // [imgN]  q fp16, O overwrites in-place
    u16* txt_h = qb + imgN;         // [txtN]
    u16* Wq_h  = txt_h + txtN;
    u16* Wk_h  = Wq_h + wN;
    u16* Wv_h  = Wk_h + wN;
    u16* Wo_h  = Wv_h + wN;
    u16* kb    = Wo_h + wN;         // [txtN]
    u16* vb    = kb + txtN;         // [txtN]

    // 1) conversions
    hipLaunchKernelGGL(conv_h, dim3((unsigned)(imgN / 8 / 256)), dim3(256),
                       0, stream, img, img_h, (int)(imgN / 8));
    Conv5Args ca;
    ca.x[0] = text; ca.h[0] = txt_h; ca.n8[0] = (int)(txtN / 8);
    ca.x[1] = Wq;   ca.h[1] = Wq_h;  ca.n8[1] = (int)(wN / 8);
    ca.x[2] = Wk;   ca.h[2] = Wk_h;  ca.n8[2] = (int)(wN / 8);
    ca.x[3] = Wv;   ca.h[3] = Wv_h;  ca.n8[3] = (int)(wN / 8);
    ca.x[4] = Wo;   ca.h[4] = Wo_h;  ca.n8[4] = (int)(wN / 8);
    hipLaunchKernelGGL(conv_h5, dim3((unsigned)((txtN / 8 + 255) / 256), 5),
                       dim3(256), 0, stream, ca);

    // 2) q projection (fp16 out): 128 x 6 tiles of 256x256
    hipLaunchKernelGGL((gemm_h_nt<0>), dim3(768), dim3(256), 0, stream,
                       img_h, Wq_h, bq, (void*)qb, Wq_h, bq, (void*)qb,
                       32768, 1536, 1536, 6);
    // 3) k,v projections fused via grid.z (fp16 out): 10 x 6 tiles
    hipLaunchKernelGGL((gemm_h_nt<0>), dim3(60, 1, 2), dim3(256), 0, stream,
                       txt_h, Wk_h, bk, (void*)kb, Wv_h, bv, (void*)vb,
                       2464, 1536, 1536, 6);
    // 4) attention (O in-place over q)
    hipLaunchKernelGGL(attn_fused, dim3(16, 8, 32), dim3(256), 0, stream,
                       qb, kb, vb, qb);
    // 5) output projection (fp32 out)
    hipLaunchKernelGGL((gemm_h_nt<1>), dim3(768), dim3(256), 0, stream,
                       qb, Wo_h, bo, d_out, Wo_h, bo, d_out,
                       32768, 1536, 1536, 6);
}

// Round 11
// 616.423 us; speedup vs baseline: 1.2963x; 1.2963x over previous
//
#include <hip/hip_runtime.h>
#include <hip/hip_bf16.h>

// ---------------------------------------------------------------------------
// lora_cross_attention, round 11: R8 skeleton + INLINE-ASM ds_read_b128.
// Rationale: plain-pointer LDS reads let the compiler's waitcnt pass insert
// its own conservative vmcnt(0) before each tile's first fragment read
// (they alias global_load_lds' LDS writes) -> every "counted vmcnt" scheme
// so far was overridden, stage distance collapsed to 0, ~900cy HBM latency
// exposed per K-tile (observed invariant ~3670cy/tile @30% MfmaUtil across
// 6 schedule variants). Inline-asm ds_read is opaque to the tracker; manual
// lgkmcnt + sched_barrier(0) gates (rule 18) make the counted pipeline real.
// GEMM: 256x256 tile, BK=32, 8 waves (2x4, each 128x64), QUAD-buffered
// 128 KB LDS, stage distance 3 K-tiles, vmcnt(8) once/tile, 2 micro-phases.
// ---------------------------------------------------------------------------

typedef unsigned short u16;
typedef _Float16 f16x8 __attribute__((ext_vector_type(8)));
typedef __attribute__((ext_vector_type(8))) short s16x8;
typedef __attribute__((ext_vector_type(4))) float f32x4;
typedef __attribute__((ext_vector_type(4))) short s16x4;

#define MFMAH(a, b, c) __builtin_amdgcn_mfma_f32_16x16x32_f16(a, b, c, 0, 0, 0)

__device__ __forceinline__ u16 f2h(float x) {
    _Float16 h = (_Float16)x;              // v_cvt_f16_f32, RNE
    return __builtin_bit_cast(u16, h);
}

__device__ __forceinline__ void gload16(const u16* g, const u16* l) {
    __builtin_amdgcn_global_load_lds(
        (const __attribute__((address_space(1))) unsigned int*)g,
        (__attribute__((address_space(3))) unsigned int*)l, 16, 0, 0);
}

// 32-bit LDS byte address for inline-asm DS ops
__device__ __forceinline__ unsigned ldsa(const u16* p) {
    return (unsigned)(size_t)(const __attribute__((address_space(3))) u16*)p;
}

// inline-asm ds_read_b128: invisible to the compiler's waitcnt tracker;
// ordering vs MFMA enforced manually via lgkmcnt + sched_barrier(0).
__device__ __forceinline__ f16x8 dsr128(unsigned byte_addr) {
    f16x8 d;
    asm volatile("ds_read_b128 %0, %1" : "=v"(d) : "v"(byte_addr));
    return d;
}

// row-hash for the 16B-chunk swizzle — (r>>1)&3 measured 0 bank conflicts
// (round 4 PMC); (r&3)^((r>>2)&3) measured 1.4e7 (rounds 3/7).
__device__ __forceinline__ int rh(int r) { return (r >> 1) & 3; }

// ---------------------------------------------------------------------------
// fp32 -> fp16 conversion
// ---------------------------------------------------------------------------
__global__ void conv_h(const float* __restrict__ x, u16* __restrict__ h, int n8) {
    const int i = blockIdx.x * 256 + threadIdx.x;
    if (i >= n8) return;
    const f32x4 a = ((const f32x4*)x)[2 * i];
    const f32x4 b = ((const f32x4*)x)[2 * i + 1];
    u16 o[8];
#pragma unroll
    for (int j = 0; j < 4; ++j) { o[j] = f2h(a[j]); o[4 + j] = f2h(b[j]); }
    *(s16x8*)&h[(size_t)i << 3] = *(s16x8*)o;
}

struct Conv5Args {
    const float* x[5];
    u16* h[5];
    int n8[5];
};

__global__ void conv_h5(Conv5Args A) {
    const int z = blockIdx.y;
    const int i = blockIdx.x * 256 + threadIdx.x;
    if (i >= A.n8[z]) return;
    const float* x = A.x[z];
    const f32x4 a = ((const f32x4*)x)[2 * i];
    const f32x4 b = ((const f32x4*)x)[2 * i + 1];
    u16 o[8];
#pragma unroll
    for (int j = 0; j < 4; ++j) { o[j] = f2h(a[j]); o[4 + j] = f2h(b[j]); }
    *(s16x8*)&A.h[z][(size_t)i << 3] = *(s16x8*)o;
}

// ---------------------------------------------------------------------------
// C[M,N] = A[M,K] x B[N,K]^T + bias, fp16 in, fp32/fp16 out.
// 256x256 tile, BK=32, 512 threads (8 waves 2x4, each 128 rows x 64 cols).
// LDS: 4 buffers x 32 KB (buf i at u16 offset i*16384; A [256][32] @+0,
// B @+8192). Row r, 16B-slot s holds global k-chunk s ^ rh(r) (both sides).
// Per K-tile TWO micro-phases:
//   P1: 8 asm ds_read (B + A rows 0-63) | 2 gload | bar | lgkm0 | 16 MFMA | bar
//   P2: 4 asm ds_read (A rows 64-127)   | 2 gload | bar | lgkm0 | 16 MFMA |
//       vmcnt(8) | bar   (gates tile t+1; 8 = tiles t+2,t+3 in flight)
// grid.z selects (B,bias,C) set 0/1 (fuses k and v projections).
// ---------------------------------------------------------------------------
template <int OUTF32>
__global__ __launch_bounds__(512, 2) void gemm_h_nt(
    const u16* __restrict__ A,
    const u16* __restrict__ B0, const float* __restrict__ bias0, void* __restrict__ C0,
    const u16* __restrict__ B1, const float* __restrict__ bias1, void* __restrict__ C1,
    int M, int N, int K, int nby) {
    __shared__ u16 lds[65536];   // 128 KB = 4 x 32 KB buffers

    const u16* B = B0; const float* bias = bias0; void* Cout = C0;
    if (blockIdx.z) { B = B1; bias = bias1; Cout = C1; }

    // XCD-bijective block swizzle (m204)
    const int nwg = gridDim.x;
    const int q8 = nwg >> 3, r8 = nwg & 7;
    const int xcd = blockIdx.x & 7, loc = blockIdx.x >> 3;
    const int wgid = (xcd < r8 ? xcd * (q8 + 1) : r8 * (q8 + 1) + (xcd - r8) * q8) + loc;
    const int bx = wgid / nby, by = wgid - bx * nby;
    const int row0 = bx * 256, col0 = by * 256;

    const int t = threadIdx.x, lane = t & 63, w = t >> 6;
    const int wr = w >> 2, wc = w & 3;
    const int l15 = lane & 15, lhi = lane >> 4;

    // staging: per tile, A = 1024 16B-chunks (256 rows x 4 slots), B same.
    // Thread t owns chunks t and 512+t of each. Global k-chunk = slot^rh(row).
    const u16* gpA[2]; const u16* gpB[2];
    int lofA[2], lofB[2];
#pragma unroll
    for (int it = 0; it < 2; ++it) {
        const int ci = it * 512 + t;
        const int row = ci >> 2, slot = ci & 3;
        const int gs = slot ^ rh(row);
        int ar = row0 + row; if (ar > M - 1) ar = M - 1;   // tail clamp (stores guarded)
        gpA[it] = A + (size_t)ar * K + (gs << 3);
        gpB[it] = B + (size_t)(col0 + row) * K + (gs << 3);
        lofA[it] = ci * 8;
        lofB[it] = 8192 + ci * 8;
    }

    // fragment read byte-offsets within a buffer (frag row = mult16 + l15).
    const int ss = rh(l15);
    const unsigned lb0 = ldsa(lds);          // LDS base byte address
    unsigned aof[8], bof[4];
#pragma unroll
    for (int i = 0; i < 8; ++i) {
        const int ar = wr * 128 + i * 16 + l15;
        aof[i] = (unsigned)((ar * 32 + ((lhi ^ ss) << 3)) * 2);
    }
#pragma unroll
    for (int n = 0; n < 4; ++n) {
        const int br = wc * 64 + n * 16 + l15;
        bof[n] = (unsigned)((8192 + br * 32 + ((lhi ^ ss) << 3)) * 2);
    }

    f32x4 acc[8][4] = {};
    const int NT = K >> 5;   // K=1536 -> 48 (>= 4 required)

#define SBAR0() __builtin_amdgcn_sched_barrier(0)
#define BARX()  do { SBAR0(); __builtin_amdgcn_s_barrier(); SBAR0(); } while (0)
#define LGKM0() do { asm volatile("s_waitcnt lgkmcnt(0)" ::: "memory"); SBAR0(); } while (0)

    // prologue: stage tiles 0,1,2 into bufs 0,1,2 (12 loads, in order)
#pragma unroll
    for (int p = 0; p < 3; ++p) {
        const size_t kp = (size_t)p << 5;
        u16* lb = lds + (p << 14);
        gload16(gpA[0] + kp, lb + lofA[0]); gload16(gpA[1] + kp, lb + lofA[1]);
        gload16(gpB[0] + kp, lb + lofB[0]); gload16(gpB[1] + kp, lb + lofB[1]);
    }
    // certify tile 0 for ALL waves: own vmcnt then barrier
    asm volatile("s_waitcnt vmcnt(8)" ::: "memory");
    BARX();

    for (int tt = 0; tt < NT; ++tt) {
        const unsigned cb = lb0 + ((unsigned)(tt & 3) << 15);   // current buf (bytes)
        u16* lsb = lds + (((tt + 3) & 3) << 14);                // stage target buf
        const int tx = (tt + 3 < NT) ? tt + 3 : tt + 3 - NT;    // wrap: vmcnt uniform
        const size_t kn = (size_t)tx << 5;

        f16x8 a0[4], a1[4], bb[4];

        // ================= phase 1 =================
        // 8 asm ds_read: B frags + A rows 0-63 (buf certified by prev barrier)
#pragma unroll
        for (int nf = 0; nf < 4; ++nf) bb[nf] = dsr128(cb + bof[nf]);
#pragma unroll
        for (int mf = 0; mf < 4; ++mf) a0[mf] = dsr128(cb + aof[mf]);
        SBAR0();
        // stage half A(t+3)
        gload16(gpA[0] + kn, lsb + lofA[0]);
        gload16(gpA[1] + kn, lsb + lofA[1]);
        BARX();
        LGKM0();                       // own 8 reads retired (rule 18 fence)
        __builtin_amdgcn_s_setprio(1);
#pragma unroll
        for (int nf = 0; nf < 4; ++nf)
#pragma unroll
            for (int mf = 0; mf < 4; ++mf)
                acc[mf][nf] = MFMAH(a0[mf], bb[nf], acc[mf][nf]);
        __builtin_amdgcn_s_setprio(0);
        BARX();

        // ================= phase 2 =================
        // 4 asm ds_read: A rows 64-127
#pragma unroll
        for (int mf = 0; mf < 4; ++mf) a1[mf] = dsr128(cb + aof[4 + mf]);
        SBAR0();
        // stage half B(t+3)
        gload16(gpB[0] + kn, lsb + lofB[0]);
        gload16(gpB[1] + kn, lsb + lofB[1]);
        BARX();
        LGKM0();
        __builtin_amdgcn_s_setprio(1);
#pragma unroll
        for (int nf = 0; nf < 4; ++nf)
#pragma unroll
            for (int mf = 0; mf < 4; ++mf)
                acc[4 + mf][nf] = MFMAH(a1[mf], bb[nf], acc[4 + mf][nf]);
        __builtin_amdgcn_s_setprio(0);
        // gate tile t+1 (oldest 4 of 12 outstanding), globalized by barrier;
        // barrier also certifies buf (t+3)&3 reusable (its readers retired
        // at iter t-1's lgkm0 gates, before this point).
        asm volatile("s_waitcnt vmcnt(8)" ::: "memory");
        BARX();
    }
    asm volatile("s_waitcnt vmcnt(0)" ::: "memory");

    // epilogue: +bias, store (C/D: col=lane&15, row=lhi*4+reg)
#pragma unroll
    for (int nf = 0; nf < 4; ++nf) {
        const int col = col0 + wc * 64 + nf * 16 + l15;
        const float bs = bias[col];
#pragma unroll
        for (int mf = 0; mf < 8; ++mf) {
            const int row = row0 + wr * 128 + mf * 16 + (lhi << 2);
#pragma unroll
            for (int r = 0; r < 4; ++r) {
                if (row + r < M) {
                    const float v = acc[mf][nf][r] + bs;
                    if (OUTF32) ((float*)Cout)[(size_t)(row + r) * N + col] = v;
                    else        ((u16*)Cout)[(size_t)(row + r) * N + col] = f2h(v);
                }
            }
        }
    }
#undef SBAR0
#undef BARX
#undef LGKM0
}

// ---------------------------------------------------------------------------
// Fused attention, fp16 in/out. One block per (qtile=64,h,b), 4 waves x 16
// q-rows. Sk=77 one-shot. O written IN-PLACE over q (each wave reads exactly
// the rows+head-slice it later writes; Q register-resident first).
// ---------------------------------------------------------------------------
#define ALDK 200
#define ALDP 104

__global__ void attn_fused(const u16* __restrict__ qbuf, const u16* __restrict__ kbuf,
                           const u16* __restrict__ vbuf, u16* __restrict__ obuf) {
    __shared__ u16 Ks[80 * ALDK];   // 32000 B
    __shared__ u16 Pls[64 * ALDP];  // 13312 B
    __shared__ u16 Vt[96 * ALDP];   // 19968 B (65280 total)

    const int t = threadIdx.x, lane = t & 63, w = t >> 6;
    const int qt = blockIdx.x, h = blockIdx.y, b = blockIdx.z;
    const int l15 = lane & 15, lhi = lane >> 4;

    // Q fragments straight from global fp16
    f16x8 qf[6];
    {
        const size_t qrow = (size_t)(b * 1024 + qt * 64 + w * 16 + l15);
        const u16* qp = qbuf + qrow * 1536 + h * 192 + (lhi << 3);
#pragma unroll
        for (int kt = 0; kt < 6; ++kt) qf[kt] = *(const f16x8*)(qp + kt * 32);
    }

    // stage K [80][192], rows >=77 zero
    for (int c = t; c < 80 * 24; c += 256) {
        const int s = c / 24, d8 = (c - s * 24) << 3;
        s16x8 val = {};
        if (s < 77) val = *(const s16x8*)&kbuf[(size_t)(b * 77 + s) * 1536 + h * 192 + d8];
        *(s16x8*)&Ks[s * ALDK + d8] = val;
    }
    // stage V^T half 0: d in [0,96); s fastest across lanes (conflict-free)
    for (int c = t; c < 96 * 12; c += 256) {
        const int s = c % 96, d8 = (c / 96) << 3;
        s16x8 val = {};
        if (s < 77) val = *(const s16x8*)&vbuf[(size_t)(b * 77 + s) * 1536 + h * 192 + d8];
#pragma unroll
        for (int j = 0; j < 8; ++j) Vt[(d8 + j) * ALDP + s] = (u16)val[j];
    }
    // zero P pad cols 80..95 (own rows)
    {
        const int row = w * 16 + l15;
        s16x4 z = {0, 0, 0, 0};
        *(s16x4*)&Pls[row * ALDP + 80 + (lhi << 2)] = z;
    }
    __syncthreads();

    // scores S[16 q-rows][80 k-cols] per wave
    f32x4 sacc[5] = {};
#pragma unroll
    for (int kt = 0; kt < 6; ++kt) {
#pragma unroll
        for (int nf = 0; nf < 5; ++nf) {
            f16x8 kf = *(const f16x8*)&Ks[(nf * 16 + l15) * ALDK + kt * 32 + (lhi << 3)];
            sacc[nf] = MFMAH(qf[kt], kf, sacc[nf]);
        }
    }

    // softmax per q-row (row = lhi*4 + r); P kept unnormalized
    float rps[4];
    const float scale = 0.07216878364870323f;   // 192^-0.5
#pragma unroll
    for (int r = 0; r < 4; ++r) {
        float m = -1e30f;
#pragma unroll
        for (int nf = 0; nf < 5; ++nf) {
            const int c = nf * 16 + l15;
            const float sv = sacc[nf][r] * scale;
            if (c < 77) m = fmaxf(m, sv);
        }
#pragma unroll
        for (int off = 1; off < 16; off <<= 1) m = fmaxf(m, __shfl_xor(m, off));
        float sum = 0.f;
#pragma unroll
        for (int nf = 0; nf < 5; ++nf) {
            const int c = nf * 16 + l15;
            const float p = (c < 77) ? __expf(sacc[nf][r] * scale - m) : 0.f;
            sacc[nf][r] = p;
            sum += p;
        }
#pragma unroll
        for (int off = 1; off < 16; off <<= 1) sum += __shfl_xor(sum, off);
        rps[r] = 1.0f / sum;   // sum >= 1
    }

    // write P (own 16 rows)
#pragma unroll
    for (int r = 0; r < 4; ++r)
#pragma unroll
        for (int nf = 0; nf < 5; ++nf)
            Pls[(w * 16 + (lhi << 2) + r) * ALDP + nf * 16 + l15] = f2h(sacc[nf][r]);
    __syncthreads();

    // P A-fragments
    f16x8 pa[3];
#pragma unroll
    for (int kt = 0; kt < 3; ++kt)
        pa[kt] = *(const f16x8*)&Pls[(w * 16 + l15) * ALDP + kt * 32 + (lhi << 3)];

    const size_t orow = (size_t)(b * 1024 + qt * 64 + w * 16 + (lhi << 2));

    // PV half 0 -> O[:, 0:96)
    {
        f32x4 oacc[6] = {};
#pragma unroll
        for (int kt = 0; kt < 3; ++kt)
#pragma unroll
            for (int nf = 0; nf < 6; ++nf) {
                f16x8 vf = *(const f16x8*)&Vt[(nf * 16 + l15) * ALDP + kt * 32 + (lhi << 3)];
                oacc[nf] = MFMAH(pa[kt], vf, oacc[nf]);
            }
#pragma unroll
        for (int nf = 0; nf < 6; ++nf) {
            const int col = h * 192 + nf * 16 + l15;
#pragma unroll
            for (int r = 0; r < 4; ++r)
                obuf[(orow + r) * 1536 + col] = f2h(oacc[nf][r] * rps[r]);
        }
    }
    __syncthreads();
    // stage V^T half 1: d in [96,192)
    for (int c = t; c < 96 * 12; c += 256) {
        const int s = c % 96, d8 = (c / 96) << 3;
        s16x8 val = {};
        if (s < 77) val = *(const s16x8*)&vbuf[(size_t)(b * 77 + s) * 1536 + h * 192 + 96 + d8];
#pragma unroll
        for (int j = 0; j < 8; ++j) Vt[(d8 + j) * ALDP + s] = (u16)val[j];
    }
    __syncthreads();
    // PV half 1 -> O[:, 96:192)
    {
        f32x4 oacc[6] = {};
#pragma unroll
        for (int kt = 0; kt < 3; ++kt)
#pragma unroll
            for (int nf = 0; nf < 6; ++nf) {
                f16x8 vf = *(const f16x8*)&Vt[(nf * 16 + l15) * ALDP + kt * 32 + (lhi << 3)];
                oacc[nf] = MFMAH(pa[kt], vf, oacc[nf]);
            }
#pragma unroll
        for (int nf = 0; nf < 6; ++nf) {
            const int col = h * 192 + 96 + nf * 16 + l15;
#pragma unroll
            for (int r = 0; r < 4; ++r)
                obuf[(orow + r) * 1536 + col] = f2h(oacc[nf][r] * rps[r]);
        }
    }
}

// ---------------------------------------------------------------------------
extern "C" void kernel_launch(void* const* d_in, const int* in_sizes, int n_in,
                              void* d_out, int out_size, void* d_ws, size_t ws_size,
                              hipStream_t stream) {
    const float* img  = (const float*)d_in[0];
    const float* text = (const float*)d_in[1];
    const float* Wq   = (const float*)d_in[2];
    const float* bq   = (const float*)d_in[3];
    const float* Wk   = (const float*)d_in[4];
    const float* bk   = (const float*)d_in[5];
    const float* Wv   = (const float*)d_in[6];
    const float* bv   = (const float*)d_in[7];
    const float* Wo   = (const float*)d_in[8];
    const float* bo   = (const float*)d_in[9];

    const size_t imgN = (size_t)32768 * 1536;
    const size_t txtN = (size_t)2464 * 1536;
    const size_t wN   = (size_t)1536 * 1536;

    // ws layout (~230 MB of fp16)
    u16* img_h = (u16*)d_ws;        // [imgN]
    u16* qb    = img_h + imgN;      // [imgN]  q fp16, O overwrites in-place
    u16* txt_h = qb + imgN;         // [txtN]
    u16* Wq_h  = txt_h + txtN;
    u16* Wk_h  = Wq_h + wN;
    u16* Wv_h  = Wk_h + wN;
    u16* Wo_h  = Wv_h + wN;
    u16* kb    = Wo_h + wN;         // [txtN]
    u16* vb    = kb + txtN;         // [txtN]

    // 1) conversions
    hipLaunchKernelGGL(conv_h, dim3((unsigned)(imgN / 8 / 256)), dim3(256),
                       0, stream, img, img_h, (int)(imgN / 8));
    Conv5Args ca;
    ca.x[0] = text; ca.h[0] = txt_h; ca.n8[0] = (int)(txtN / 8);
    ca.x[1] = Wq;   ca.h[1] = Wq_h;  ca.n8[1] = (int)(wN / 8);
    ca.x[2] = Wk;   ca.h[2] = Wk_h;  ca.n8[2] = (int)(wN / 8);
    ca.x[3] = Wv;   ca.h[3] = Wv_h;  ca.n8[3] = (int)(wN / 8);
    ca.x[4] = Wo;   ca.h[4] = Wo_h;  ca.n8[4] = (int)(wN / 8);
    hipLaunchKernelGGL(conv_h5, dim3((unsigned)((txtN / 8 + 255) / 256), 5),
                       dim3(256), 0, stream, ca);

    // 2) q projection (fp16 out): 128 x 6 tiles of 256x256
    hipLaunchKernelGGL((gemm_h_nt<0>), dim3(768), dim3(512), 0, stream,
                       img_h, Wq_h, bq, (void*)qb, Wq_h, bq, (void*)qb,
                       32768, 1536, 1536, 6);
    // 3) k,v projections fused via grid.z (fp16 out): 10 x 6 tiles
    hipLaunchKernelGGL((gemm_h_nt<0>), dim3(60, 1, 2), dim3(512), 0, stream,
                       txt_h, Wk_h, bk, (void*)kb, Wv_h, bv, (void*)vb,
                       2464, 1536, 1536, 6);
    // 4) attention (O in-place over q)
    hipLaunchKernelGGL(attn_fused, dim3(16, 8, 32), dim3(256), 0, stream,
                       qb, kb, vb, qb);
    // 5) output projection (fp32 out)
    hipLaunchKernelGGL((gemm_h_nt<1>), dim3(768), dim3(512), 0, stream,
                       qb, Wo_h, bo, d_out, Wo_h, bo, d_out,
                       32768, 1536, 1536, 6);
}

// Round 12
// 606.380 us; speedup vs baseline: 1.3178x; 1.0166x over previous
//
#include <hip/hip_runtime.h>
#include <hip/hip_bf16.h>

// ---------------------------------------------------------------------------
// lora_cross_attention, round 12: cross-tile software-pipelined LDS reads.
// The 7-variant invariant (684 TF, MfmaUtil 30%) = read-burst and MFMA-burst
// never overlap: reads were always issued and lgkm-waited in the same phase
// as their MFMA. Fix: issue tile t+1's ds_reads DURING tile t's MFMA
// clusters (buf t+1 certified one barrier ago; quad-buffer distance-3),
// gate with COUNTED lgkm (DS retires in order), ONE barrier per tile.
// GEMM: 256x256 tile, BK=32, 8 waves (2x4, each 128x64), 4x32KB LDS.
// ---------------------------------------------------------------------------

typedef unsigned short u16;
typedef _Float16 f16x8 __attribute__((ext_vector_type(8)));
typedef __attribute__((ext_vector_type(8))) short s16x8;
typedef __attribute__((ext_vector_type(4))) float f32x4;
typedef __attribute__((ext_vector_type(4))) short s16x4;

#define MFMAH(a, b, c) __builtin_amdgcn_mfma_f32_16x16x32_f16(a, b, c, 0, 0, 0)

__device__ __forceinline__ u16 f2h(float x) {
    _Float16 h = (_Float16)x;              // v_cvt_f16_f32, RNE
    return __builtin_bit_cast(u16, h);
}

__device__ __forceinline__ void gload16(const u16* g, const u16* l) {
    __builtin_amdgcn_global_load_lds(
        (const __attribute__((address_space(1))) unsigned int*)g,
        (__attribute__((address_space(3))) unsigned int*)l, 16, 0, 0);
}

// 32-bit LDS byte address for inline-asm DS ops
__device__ __forceinline__ unsigned ldsa(const u16* p) {
    return (unsigned)(size_t)(const __attribute__((address_space(3))) u16*)p;
}

// inline-asm ds_read_b128 (volatile: stays ordered vs the counted waits)
__device__ __forceinline__ f16x8 dsr128(unsigned byte_addr) {
    f16x8 d;
    asm volatile("ds_read_b128 %0, %1" : "=v"(d) : "v"(byte_addr));
    return d;
}

// row-hash for the 16B-chunk swizzle — (r>>1)&3 measured 0 bank conflicts.
__device__ __forceinline__ int rh(int r) { return (r >> 1) & 3; }

// ---------------------------------------------------------------------------
// fp32 -> fp16 conversion
// ---------------------------------------------------------------------------
__global__ void conv_h(const float* __restrict__ x, u16* __restrict__ h, int n8) {
    const int i = blockIdx.x * 256 + threadIdx.x;
    if (i >= n8) return;
    const f32x4 a = ((const f32x4*)x)[2 * i];
    const f32x4 b = ((const f32x4*)x)[2 * i + 1];
    u16 o[8];
#pragma unroll
    for (int j = 0; j < 4; ++j) { o[j] = f2h(a[j]); o[4 + j] = f2h(b[j]); }
    *(s16x8*)&h[(size_t)i << 3] = *(s16x8*)o;
}

struct Conv5Args {
    const float* x[5];
    u16* h[5];
    int n8[5];
};

__global__ void conv_h5(Conv5Args A) {
    const int z = blockIdx.y;
    const int i = blockIdx.x * 256 + threadIdx.x;
    if (i >= A.n8[z]) return;
    const float* x = A.x[z];
    const f32x4 a = ((const f32x4*)x)[2 * i];
    const f32x4 b = ((const f32x4*)x)[2 * i + 1];
    u16 o[8];
#pragma unroll
    for (int j = 0; j < 4; ++j) { o[j] = f2h(a[j]); o[4 + j] = f2h(b[j]); }
    *(s16x8*)&A.h[z][(size_t)i << 3] = *(s16x8*)o;
}

// ---------------------------------------------------------------------------
// C[M,N] = A[M,K] x B[N,K]^T + bias, fp16 in, fp32/fp16 out.
// 256x256 tile, BK=32, 512 threads (8 waves 2x4, each 128 rows x 64 cols).
// LDS: 4 buffers x 32 KB (buf i at u16 offset i*16384; A [256][32] @+0,
// B @+8192). Row r, 16B-slot s holds global k-chunk s ^ rh(r) (both sides).
// Per tile (ONE barrier):
//   stage A(t+3) | read Ahigh(t) | lgkm(4): [B,Alow](t) ready | MFMA-low |
//   read Alow(t+1) | stage B(t+3) | lgkm(4): Ahigh(t) ready | MFMA-high |
//   read B(t+1) | vmcnt(4): certify t+2 | s_barrier.
// Reads for a tile are issued one MFMA-cluster-or-more ahead of their lgkm
// gate -> LDS service overlaps the MFMA pipe.
// grid.z selects (B,bias,C) set 0/1 (fuses k and v projections).
// ---------------------------------------------------------------------------
template <int OUTF32>
__global__ __launch_bounds__(512, 2) void gemm_h_nt(
    const u16* __restrict__ A,
    const u16* __restrict__ B0, const float* __restrict__ bias0, void* __restrict__ C0,
    const u16* __restrict__ B1, const float* __restrict__ bias1, void* __restrict__ C1,
    int M, int N, int K, int nby) {
    __shared__ u16 lds[65536];   // 128 KB = 4 x 32 KB buffers

    const u16* B = B0; const float* bias = bias0; void* Cout = C0;
    if (blockIdx.z) { B = B1; bias = bias1; Cout = C1; }

    // XCD-bijective block swizzle (m204)
    const int nwg = gridDim.x;
    const int q8 = nwg >> 3, r8 = nwg & 7;
    const int xcd = blockIdx.x & 7, loc = blockIdx.x >> 3;
    const int wgid = (xcd < r8 ? xcd * (q8 + 1) : r8 * (q8 + 1) + (xcd - r8) * q8) + loc;
    const int bx = wgid / nby, by = wgid - bx * nby;
    const int row0 = bx * 256, col0 = by * 256;

    const int t = threadIdx.x, lane = t & 63, w = t >> 6;
    const int wr = w >> 2, wc = w & 3;
    const int l15 = lane & 15, lhi = lane >> 4;

    // staging: per tile, A = 1024 16B-chunks (256 rows x 4 slots), B same.
    // Thread t owns chunks t and 512+t of each. Global k-chunk = slot^rh(row).
    const u16* gpA[2]; const u16* gpB[2];
    int lofA[2], lofB[2];
#pragma unroll
    for (int it = 0; it < 2; ++it) {
        const int ci = it * 512 + t;
        const int row = ci >> 2, slot = ci & 3;
        const int gs = slot ^ rh(row);
        int ar = row0 + row; if (ar > M - 1) ar = M - 1;   // tail clamp (stores guarded)
        gpA[it] = A + (size_t)ar * K + (gs << 3);
        gpB[it] = B + (size_t)(col0 + row) * K + (gs << 3);
        lofA[it] = ci * 8;
        lofB[it] = 8192 + ci * 8;
    }

    // fragment read byte-offsets within a buffer (frag row = mult16 + l15).
    const int ss = rh(l15);
    const unsigned lb0 = ldsa(lds);
    unsigned aof[8], bof[4];
#pragma unroll
    for (int i = 0; i < 8; ++i) {
        const int ar = wr * 128 + i * 16 + l15;
        aof[i] = (unsigned)((ar * 32 + ((lhi ^ ss) << 3)) * 2);
    }
#pragma unroll
    for (int n = 0; n < 4; ++n) {
        const int br = wc * 64 + n * 16 + l15;
        bof[n] = (unsigned)((8192 + br * 32 + ((lhi ^ ss) << 3)) * 2);
    }

    f32x4 acc[8][4] = {};
    const int NT = K >> 5;   // K=1536 -> 48 (>= 4 required)

#define SBAR0() __builtin_amdgcn_sched_barrier(0)
#define BARX()  do { SBAR0(); __builtin_amdgcn_s_barrier(); SBAR0(); } while (0)

    // prologue: stage tiles 0,1,2 into bufs 0,1,2 (12 gloads, in order)
#pragma unroll
    for (int p = 0; p < 3; ++p) {
        const size_t kp = (size_t)p << 5;
        u16* lb = lds + (p << 14);
        gload16(gpA[0] + kp, lb + lofA[0]); gload16(gpA[1] + kp, lb + lofA[1]);
        gload16(gpB[0] + kp, lb + lofB[0]); gload16(gpB[1] + kp, lb + lofB[1]);
    }
    // certify tiles 0,1 (8 oldest retired; tile 2's 4 stay in flight)
    asm volatile("s_waitcnt vmcnt(4)" ::: "memory");
    BARX();

    // pre-issue tile 0's B and A-low reads (loop-carried frag banks)
    f16x8 al[4], ah[4], bb[4];
#pragma unroll
    for (int nf = 0; nf < 4; ++nf) bb[nf] = dsr128(lb0 + bof[nf]);
#pragma unroll
    for (int mf = 0; mf < 4; ++mf) al[mf] = dsr128(lb0 + aof[mf]);
    SBAR0();

    for (int tt = 0; tt < NT; ++tt) {
        const unsigned cb = lb0 + ((unsigned)(tt & 3) << 15);        // current buf
        const unsigned nb = lb0 + ((unsigned)((tt + 1) & 3) << 15);  // next buf (certified)
        u16* lsb = lds + (((tt + 3) & 3) << 14);                     // stage target
        const int tx = (tt + 3 < NT) ? tt + 3 : tt + 3 - NT;         // wrap: counts uniform
        const size_t kn = (size_t)tx << 5;

        // stage A(t+3)
        gload16(gpA[0] + kn, lsb + lofA[0]);
        gload16(gpA[1] + kn, lsb + lofA[1]);
        // issue Ahigh(t)
#pragma unroll
        for (int mf = 0; mf < 4; ++mf) ah[mf] = dsr128(cb + aof[4 + mf]);
        SBAR0();
        // gate: [B,Alow](t) retired (issued last iter; Ahigh(t) 4 stay out)
        asm volatile("s_waitcnt lgkmcnt(4)" ::: "memory");
        SBAR0();
        __builtin_amdgcn_s_setprio(1);
#pragma unroll
        for (int nf = 0; nf < 4; ++nf)
#pragma unroll
            for (int mf = 0; mf < 4; ++mf)
                acc[mf][nf] = MFMAH(al[mf], bb[nf], acc[mf][nf]);
        __builtin_amdgcn_s_setprio(0);
        // issue Alow(t+1) (al bank dead after MFMA-low; SSA keeps both live briefly)
#pragma unroll
        for (int mf = 0; mf < 4; ++mf) al[mf] = dsr128(nb + aof[mf]);
        SBAR0();
        // stage B(t+3)
        gload16(gpB[0] + kn, lsb + lofB[0]);
        gload16(gpB[1] + kn, lsb + lofB[1]);
        // gate: Ahigh(t) retired (Alow(t+1) 4 stay out)
        asm volatile("s_waitcnt lgkmcnt(4)" ::: "memory");
        SBAR0();
        __builtin_amdgcn_s_setprio(1);
#pragma unroll
        for (int nf = 0; nf < 4; ++nf)
#pragma unroll
            for (int mf = 0; mf < 4; ++mf)
                acc[4 + mf][nf] = MFMAH(ah[mf], bb[nf], acc[4 + mf][nf]);
        __builtin_amdgcn_s_setprio(0);
        // issue B(t+1)
#pragma unroll
        for (int nf = 0; nf < 4; ++nf) bb[nf] = dsr128(nb + bof[nf]);
        SBAR0();
        // certify tile t+2 (in flight: t+2's 4 + t+3's 4; keep 4) + globalize
        asm volatile("s_waitcnt vmcnt(4)" ::: "memory");
        BARX();
    }
    asm volatile("s_waitcnt vmcnt(0) lgkmcnt(0)" ::: "memory");

    // epilogue: +bias, store (C/D: col=lane&15, row=lhi*4+reg)
#pragma unroll
    for (int nf = 0; nf < 4; ++nf) {
        const int col = col0 + wc * 64 + nf * 16 + l15;
        const float bs = bias[col];
#pragma unroll
        for (int mf = 0; mf < 8; ++mf) {
            const int row = row0 + wr * 128 + mf * 16 + (lhi << 2);
#pragma unroll
            for (int r = 0; r < 4; ++r) {
                if (row + r < M) {
                    const float v = acc[mf][nf][r] + bs;
                    if (OUTF32) ((float*)Cout)[(size_t)(row + r) * N + col] = v;
                    else        ((u16*)Cout)[(size_t)(row + r) * N + col] = f2h(v);
                }
            }
        }
    }
#undef SBAR0
#undef BARX
}

// ---------------------------------------------------------------------------
// Fused attention, fp16 in/out. One block per (qtile=64,h,b), 4 waves x 16
// q-rows. Sk=77 one-shot. O written IN-PLACE over q (each wave reads exactly
// the rows+head-slice it later writes; Q register-resident first).
// ---------------------------------------------------------------------------
#define ALDK 200
#define ALDP 104

__global__ void attn_fused(const u16* __restrict__ qbuf, const u16* __restrict__ kbuf,
                           const u16* __restrict__ vbuf, u16* __restrict__ obuf) {
    __shared__ u16 Ks[80 * ALDK];   // 32000 B
    __shared__ u16 Pls[64 * ALDP];  // 13312 B
    __shared__ u16 Vt[96 * ALDP];   // 19968 B (65280 total)

    const int t = threadIdx.x, lane = t & 63, w = t >> 6;
    const int qt = blockIdx.x, h = blockIdx.y, b = blockIdx.z;
    const int l15 = lane & 15, lhi = lane >> 4;

    // Q fragments straight from global fp16
    f16x8 qf[6];
    {
        const size_t qrow = (size_t)(b * 1024 + qt * 64 + w * 16 + l15);
        const u16* qp = qbuf + qrow * 1536 + h * 192 + (lhi << 3);
#pragma unroll
        for (int kt = 0; kt < 6; ++kt) qf[kt] = *(const f16x8*)(qp + kt * 32);
    }

    // stage K [80][192], rows >=77 zero
    for (int c = t; c < 80 * 24; c += 256) {
        const int s = c / 24, d8 = (c - s * 24) << 3;
        s16x8 val = {};
        if (s < 77) val = *(const s16x8*)&kbuf[(size_t)(b * 77 + s) * 1536 + h * 192 + d8];
        *(s16x8*)&Ks[s * ALDK + d8] = val;
    }
    // stage V^T half 0: d in [0,96); s fastest across lanes (conflict-free)
    for (int c = t; c < 96 * 12; c += 256) {
        const int s = c % 96, d8 = (c / 96) << 3;
        s16x8 val = {};
        if (s < 77) val = *(const s16x8*)&vbuf[(size_t)(b * 77 + s) * 1536 + h * 192 + d8];
#pragma unroll
        for (int j = 0; j < 8; ++j) Vt[(d8 + j) * ALDP + s] = (u16)val[j];
    }
    // zero P pad cols 80..95 (own rows)
    {
        const int row = w * 16 + l15;
        s16x4 z = {0, 0, 0, 0};
        *(s16x4*)&Pls[row * ALDP + 80 + (lhi << 2)] = z;
    }
    __syncthreads();

    // scores S[16 q-rows][80 k-cols] per wave
    f32x4 sacc[5] = {};
#pragma unroll
    for (int kt = 0; kt < 6; ++kt) {
#pragma unroll
        for (int nf = 0; nf < 5; ++nf) {
            f16x8 kf = *(const f16x8*)&Ks[(nf * 16 + l15) * ALDK + kt * 32 + (lhi << 3)];
            sacc[nf] = MFMAH(qf[kt], kf, sacc[nf]);
        }
    }

    // softmax per q-row (row = lhi*4 + r); P kept unnormalized
    float rps[4];
    const float scale = 0.07216878364870323f;   // 192^-0.5
#pragma unroll
    for (int r = 0; r < 4; ++r) {
        float m = -1e30f;
#pragma unroll
        for (int nf = 0; nf < 5; ++nf) {
            const int c = nf * 16 + l15;
            const float sv = sacc[nf][r] * scale;
            if (c < 77) m = fmaxf(m, sv);
        }
#pragma unroll
        for (int off = 1; off < 16; off <<= 1) m = fmaxf(m, __shfl_xor(m, off));
        float sum = 0.f;
#pragma unroll
        for (int nf = 0; nf < 5; ++nf) {
            const int c = nf * 16 + l15;
            const float p = (c < 77) ? __expf(sacc[nf][r] * scale - m) : 0.f;
            sacc[nf][r] = p;
            sum += p;
        }
#pragma unroll
        for (int off = 1; off < 16; off <<= 1) sum += __shfl_xor(sum, off);
        rps[r] = 1.0f / sum;   // sum >= 1
    }

    // write P (own 16 rows)
#pragma unroll
    for (int r = 0; r < 4; ++r)
#pragma unroll
        for (int nf = 0; nf < 5; ++nf)
            Pls[(w * 16 + (lhi << 2) + r) * ALDP + nf * 16 + l15] = f2h(sacc[nf][r]);
    __syncthreads();

    // P A-fragments
    f16x8 pa[3];
#pragma unroll
    for (int kt = 0; kt < 3; ++kt)
        pa[kt] = *(const f16x8*)&Pls[(w * 16 + l15) * ALDP + kt * 32 + (lhi << 3)];

    const size_t orow = (size_t)(b * 1024 + qt * 64 + w * 16 + (lhi << 2));

    // PV half 0 -> O[:, 0:96)
    {
        f32x4 oacc[6] = {};
#pragma unroll
        for (int kt = 0; kt < 3; ++kt)
#pragma unroll
            for (int nf = 0; nf < 6; ++nf) {
                f16x8 vf = *(const f16x8*)&Vt[(nf * 16 + l15) * ALDP + kt * 32 + (lhi << 3)];
                oacc[nf] = MFMAH(pa[kt], vf, oacc[nf]);
            }
#pragma unroll
        for (int nf = 0; nf < 6; ++nf) {
            const int col = h * 192 + nf * 16 + l15;
#pragma unroll
            for (int r = 0; r < 4; ++r)
                obuf[(orow + r) * 1536 + col] = f2h(oacc[nf][r] * rps[r]);
        }
    }
    __syncthreads();
    // stage V^T half 1: d in [96,192)
    for (int c = t; c < 96 * 12; c += 256) {
        const int s = c % 96, d8 = (c / 96) << 3;
        s16x8 val = {};
        if (s < 77) val = *(const s16x8*)&vbuf[(size_t)(b * 77 + s) * 1536 + h * 192 + 96 + d8];
#pragma unroll
        for (int j = 0; j < 8; ++j) Vt[(d8 + j) * ALDP + s] = (u16)val[j];
    }
    __syncthreads();
    // PV half 1 -> O[:, 96:192)
    {
        f32x4 oacc[6] = {};
#pragma unroll
        for (int kt = 0; kt < 3; ++kt)
#pragma unroll
            for (int nf = 0; nf < 6; ++nf) {
                f16x8 vf = *(const f16x8*)&Vt[(nf * 16 + l15) * ALDP + kt * 32 + (lhi << 3)];
                oacc[nf] = MFMAH(pa[kt], vf, oacc[nf]);
            }
#pragma unroll
        for (int nf = 0; nf < 6; ++nf) {
            const int col = h * 192 + 96 + nf * 16 + l15;
#pragma unroll
            for (int r = 0; r < 4; ++r)
                obuf[(orow + r) * 1536 + col] = f2h(oacc[nf][r] * rps[r]);
        }
    }
}

// ---------------------------------------------------------------------------
extern "C" void kernel_launch(void* const* d_in, const int* in_sizes, int n_in,
                              void* d_out, int out_size, void* d_ws, size_t ws_size,
                              hipStream_t stream) {
    const float* img  = (const float*)d_in[0];
    const float* text = (const float*)d_in[1];
    const float* Wq   = (const float*)d_in[2];
    const float* bq   = (const float*)d_in[3];
    const float* Wk   = (const float*)d_in[4];
    const float* bk   = (const float*)d_in[5];
    const float* Wv   = (const float*)d_in[6];
    const float* bv   = (const float*)d_in[7];
    const float* Wo   = (const float*)d_in[8];
    const float* bo   = (const float*)d_in[9];

    const size_t imgN = (size_t)32768 * 1536;
    const size_t txtN = (size_t)2464 * 1536;
    const size_t wN   = (size_t)1536 * 1536;

    // ws layout (~230 MB of fp16)
    u16* img_h = (u16*)d_ws;        // [imgN]
    u16* qb    = img_h + imgN;      // [imgN]  q fp16, O overwrites in-place
    u16* txt_h = qb + imgN;         // [txtN]
    u16* Wq_h  = txt_h + txtN;
    u16* Wk_h  = Wq_h + wN;
    u16* Wv_h  = Wk_h + wN;
    u16* Wo_h  = Wv_h + wN;
    u16* kb    = Wo_h + wN;         // [txtN]
    u16* vb    = kb + txtN;         // [txtN]

    // 1) conversions
    hipLaunchKernelGGL(conv_h, dim3((unsigned)(imgN / 8 / 256)), dim3(256),
                       0, stream, img, img_h, (int)(imgN / 8));
    Conv5Args ca;
    ca.x[0] = text; ca.h[0] = txt_h; ca.n8[0] = (int)(txtN / 8);
    ca.x[1] = Wq;   ca.h[1] = Wq_h;  ca.n8[1] = (int)(wN / 8);
    ca.x[2] = Wk;   ca.h[2] = Wk_h;  ca.n8[2] = (int)(wN / 8);
    ca.x[3] = Wv;   ca.h[3] = Wv_h;  ca.n8[3] = (int)(wN / 8);
    ca.x[4] = Wo;   ca.h[4] = Wo_h;  ca.n8[4] = (int)(wN / 8);
    hipLaunchKernelGGL(conv_h5, dim3((unsigned)((txtN / 8 + 255) / 256), 5),
                       dim3(256), 0, stream, ca);

    // 2) q projection (fp16 out): 128 x 6 tiles of 256x256
    hipLaunchKernelGGL((gemm_h_nt<0>), dim3(768), dim3(512), 0, stream,
                       img_h, Wq_h, bq, (void*)qb, Wq_h, bq, (void*)qb,
                       32768, 1536, 1536, 6);
    // 3) k,v projections fused via grid.z (fp16 out): 10 x 6 tiles
    hipLaunchKernelGGL((gemm_h_nt<0>), dim3(60, 1, 2), dim3(512), 0, stream,
                       txt_h, Wk_h, bk, (void*)kb, Wv_h, bv, (void*)vb,
                       2464, 1536, 1536, 6);
    // 4) attention (O in-place over q)
    hipLaunchKernelGGL(attn_fused, dim3(16, 8, 32), dim3(256), 0, stream,
                       qb, kb, vb, qb);
    // 5) output projection (fp32 out)
    hipLaunchKernelGGL((gemm_h_nt<1>), dim3(768), dim3(512), 0, stream,
                       qb, Wo_h, bo, d_out, Wo_h, bo, d_out,
                       32768, 1536, 1536, 6);
}

// Round 13
// 592.332 us; speedup vs baseline: 1.3490x; 1.0237x over previous
//
#include <hip/hip_runtime.h>
#include <hip/hip_bf16.h>

// ---------------------------------------------------------------------------
// lora_cross_attention, round 13: system-level fusion.
// GEMM schedule is at its reproducible ceiling (~700 TF across 8 variants);
// this round removes whole passes instead:
//   - conv_h(img) FUSED into q-proj (reg-staged fp32 A -> cvt -> ds_write,
//     classic 1-sync double buffer)  => -300 MB traffic, -1 launch
//   - q,k,v in ONE launch (grid.z): kv's 120 blocks fill q's round gaps
//   - out-proj: best-measured R12 pipelined kernel, verbatim
//   - attention: unchanged (known-good)
// ---------------------------------------------------------------------------

typedef unsigned short u16;
typedef _Float16 f16x8 __attribute__((ext_vector_type(8)));
typedef __attribute__((ext_vector_type(8))) short s16x8;
typedef __attribute__((ext_vector_type(4))) float f32x4;
typedef __attribute__((ext_vector_type(4))) short s16x4;

#define MFMAH(a, b, c) __builtin_amdgcn_mfma_f32_16x16x32_f16(a, b, c, 0, 0, 0)

__device__ __forceinline__ u16 f2h(float x) {
    _Float16 h = (_Float16)x;              // v_cvt_f16_f32, RNE
    return __builtin_bit_cast(u16, h);
}

__device__ __forceinline__ void gload16(const u16* g, const u16* l) {
    __builtin_amdgcn_global_load_lds(
        (const __attribute__((address_space(1))) unsigned int*)g,
        (__attribute__((address_space(3))) unsigned int*)l, 16, 0, 0);
}

// 32-bit LDS byte address for inline-asm DS ops
__device__ __forceinline__ unsigned ldsa(const u16* p) {
    return (unsigned)(size_t)(const __attribute__((address_space(3))) u16*)p;
}

__device__ __forceinline__ f16x8 dsr128(unsigned byte_addr) {
    f16x8 d;
    asm volatile("ds_read_b128 %0, %1" : "=v"(d) : "v"(byte_addr));
    return d;
}

// row-hash for the 16B-chunk swizzle — (r>>1)&3 measured 0 bank conflicts.
__device__ __forceinline__ int rh(int r) { return (r >> 1) & 3; }

// ---------------------------------------------------------------------------
// fp32 -> fp16 conversion for text + 4 weights (img conversion fused into qkv)
// ---------------------------------------------------------------------------
struct Conv5Args {
    const float* x[5];
    u16* h[5];
    int n8[5];
};

__global__ void conv_h5(Conv5Args A) {
    const int z = blockIdx.y;
    const int i = blockIdx.x * 256 + threadIdx.x;
    if (i >= A.n8[z]) return;
    const float* x = A.x[z];
    const f32x4 a = ((const f32x4*)x)[2 * i];
    const f32x4 b = ((const f32x4*)x)[2 * i + 1];
    u16 o[8];
#pragma unroll
    for (int j = 0; j < 4; ++j) { o[j] = f2h(a[j]); o[4 + j] = f2h(b[j]); }
    *(s16x8*)&A.h[z][(size_t)i << 3] = *(s16x8*)o;
}

// ---------------------------------------------------------------------------
// Fused q/k/v projection. grid.z: 0 -> q = img(F32, converted in-kernel) x Wq,
// 1 -> k = txt_h x Wk, 2 -> v = txt_h x Wv. All fp16 out.
// 256x256 tile, BK=32, 512 threads (8 waves 2x4, each 128x64).
// LDS 64 KB = 2 x 32 KB double buffer (A @+0, B @+8192 u16 within buffer).
// Classic 1-sync/tile dbuf: sync | stage(t+1 -> buf^1) | compute buf(t).
// z=0 A-staging: f32 global -> regs (issued prev iter) -> cvt -> ds_write_b128
// (pre-swizzled source, linear LDS; same layout as gload path).
// ---------------------------------------------------------------------------
__global__ __launch_bounds__(512, 2) void qkv_gemm(
    const float* __restrict__ imgF, const u16* __restrict__ txtH,
    const u16* __restrict__ Wq, const u16* __restrict__ Wk, const u16* __restrict__ Wv,
    const float* __restrict__ bq, const float* __restrict__ bk, const float* __restrict__ bv,
    u16* __restrict__ qb, u16* __restrict__ kb, u16* __restrict__ vb) {
    constexpr int K = 1536;
    const int z = blockIdx.z;
    const int nwg = z ? 60 : 768;
    if ((int)blockIdx.x >= nwg) return;
    const int M = z ? 2464 : 32768;
    const u16* B = (z == 0) ? Wq : (z == 1 ? Wk : Wv);
    const float* bias = (z == 0) ? bq : (z == 1 ? bk : bv);
    u16* Cout = (z == 0) ? qb : (z == 1 ? kb : vb);

    __shared__ u16 lds[32768];   // 64 KB: buf c at u16 offset c*16384

    // XCD-bijective block swizzle (m204)
    const int q8 = nwg >> 3, r8 = nwg & 7;
    const int xcd = blockIdx.x & 7, loc = blockIdx.x >> 3;
    const int wgid = (xcd < r8 ? xcd * (q8 + 1) : r8 * (q8 + 1) + (xcd - r8) * q8) + loc;
    const int bx = wgid / 6, by = wgid - bx * 6;
    const int row0 = bx * 256, col0 = by * 256;

    const int t = threadIdx.x, lane = t & 63, w = t >> 6;
    const int wr = w >> 2, wc = w & 3;
    const int l15 = lane & 15, lhi = lane >> 4;

    // staging geometry: A/B tile = 1024 16B-chunks (256 rows x 4 slots);
    // thread t owns chunks t and 512+t. Global k-chunk = slot ^ rh(row).
    const float* gfA[2];       // z=0: f32 A source
    const u16* gpA[2];         // z>0: f16 A source
    const u16* gpB[2];
    int lofA[2], lofB[2];
#pragma unroll
    for (int it = 0; it < 2; ++it) {
        const int ci = it * 512 + t;
        const int row = ci >> 2, slot = ci & 3;
        const int gs = slot ^ rh(row);
        int ar = row0 + row; if (ar > M - 1) ar = M - 1;   // tail clamp (stores guarded)
        gfA[it] = imgF + (size_t)ar * K + (gs << 3);
        gpA[it] = txtH + (size_t)ar * K + (gs << 3);
        gpB[it] = B + (size_t)(col0 + row) * K + (gs << 3);
        lofA[it] = ci * 8;
        lofB[it] = 8192 + ci * 8;
    }

    // fragment read offsets
    const int ss = rh(l15);
    int aof[8], bof[4];
#pragma unroll
    for (int i = 0; i < 8; ++i) {
        const int ar = wr * 128 + i * 16 + l15;
        aof[i] = ar * 32 + ((lhi ^ ss) << 3);
    }
#pragma unroll
    for (int n = 0; n < 4; ++n) {
        const int br = wc * 64 + n * 16 + l15;
        bof[n] = 8192 + br * 32 + ((lhi ^ ss) << 3);
    }

    f32x4 acc[8][4] = {};
    const int NT = K >> 5;   // 48

    // ---- staging helpers ----
    f32x4 af[2][2];          // z=0: f32 A chunks for the NEXT staged tile
#define LOADAF(kk) do { \
        af[0][0] = *(const f32x4*)(gfA[0] + (kk)); \
        af[0][1] = *(const f32x4*)(gfA[0] + (kk) + 4); \
        af[1][0] = *(const f32x4*)(gfA[1] + (kk)); \
        af[1][1] = *(const f32x4*)(gfA[1] + (kk) + 4); } while (0)
#define WRITEA(bufo) do { \
        _Pragma("unroll") for (int it = 0; it < 2; ++it) { \
            u16 hh[8]; \
            _Pragma("unroll") for (int j = 0; j < 4; ++j) { \
                hh[j] = f2h(af[it][0][j]); hh[4 + j] = f2h(af[it][1][j]); } \
            *(s16x8*)&lds[(bufo) + lofA[it]] = *(s16x8*)hh; } } while (0)

    // prologue: stage tile 0 into buf 0
    if (z == 0) {
        LOADAF(0);
        WRITEA(0);
        LOADAF(32);            // for tile 1
    } else {
        gload16(gpA[0], lds + lofA[0]);
        gload16(gpA[1], lds + lofA[1]);
    }
    gload16(gpB[0], lds + lofB[0]);
    gload16(gpB[1], lds + lofB[1]);

    for (int tt = 0; tt < NT; ++tt) {
        const int cb = (tt & 1) << 14;
        const int nb = ((tt & 1) ^ 1) << 14;
        __syncthreads();   // buf(tt) staged (drains vm+lgkm); buf^1 readers done

        if (tt + 1 < NT) {
            const size_t kn = (size_t)(tt + 1) << 5;
            if (z == 0) {
                WRITEA(nb);                                  // uses af loaded last iter
                const size_t kn2 = (tt + 2 < NT) ? ((size_t)(tt + 2) << 5) : 0;
                LOADAF(kn2);                                 // overlaps compute below
            } else {
                gload16(gpA[0] + kn, lds + nb + lofA[0]);
                gload16(gpA[1] + kn, lds + nb + lofA[1]);
            }
            gload16(gpB[0] + kn, lds + nb + lofB[0]);
            gload16(gpB[1] + kn, lds + nb + lofB[1]);
        }

        f16x8 a[8];
#pragma unroll
        for (int mf = 0; mf < 8; ++mf) a[mf] = *(const f16x8*)&lds[cb + aof[mf]];
#pragma unroll
        for (int nf = 0; nf < 4; ++nf) {
            const f16x8 bfr = *(const f16x8*)&lds[cb + bof[nf]];
#pragma unroll
            for (int mf = 0; mf < 8; ++mf)
                acc[mf][nf] = MFMAH(a[mf], bfr, acc[mf][nf]);
        }
    }
#undef LOADAF
#undef WRITEA

    // epilogue: +bias, fp16 store (C/D: col=lane&15, row=lhi*4+reg)
#pragma unroll
    for (int nf = 0; nf < 4; ++nf) {
        const int col = col0 + wc * 64 + nf * 16 + l15;
        const float bs = bias[col];
#pragma unroll
        for (int mf = 0; mf < 8; ++mf) {
            const int row = row0 + wr * 128 + mf * 16 + (lhi << 2);
#pragma unroll
            for (int r = 0; r < 4; ++r) {
                if (row + r < M)
                    Cout[(size_t)(row + r) * 1536 + col] = f2h(acc[mf][nf][r] + bs);
            }
        }
    }
}

// ---------------------------------------------------------------------------
// Output projection: R12 kernel verbatim (best measured: 217 us, fp32 out).
// 256x256 tile, BK=32, 8 waves, 4x32KB LDS, stage distance 3, counted
// lgkm/vmcnt, cross-tile pipelined asm ds_reads.
// ---------------------------------------------------------------------------
template <int OUTF32>
__global__ __launch_bounds__(512, 2) void gemm_h_nt(
    const u16* __restrict__ A,
    const u16* __restrict__ B0, const float* __restrict__ bias0, void* __restrict__ C0,
    const u16* __restrict__ B1, const float* __restrict__ bias1, void* __restrict__ C1,
    int M, int N, int K, int nby) {
    __shared__ u16 lds[65536];   // 128 KB = 4 x 32 KB buffers

    const u16* B = B0; const float* bias = bias0; void* Cout = C0;
    if (blockIdx.z) { B = B1; bias = bias1; Cout = C1; }

    const int nwg = gridDim.x;
    const int q8 = nwg >> 3, r8 = nwg & 7;
    const int xcd = blockIdx.x & 7, loc = blockIdx.x >> 3;
    const int wgid = (xcd < r8 ? xcd * (q8 + 1) : r8 * (q8 + 1) + (xcd - r8) * q8) + loc;
    const int bx = wgid / nby, by = wgid - bx * nby;
    const int row0 = bx * 256, col0 = by * 256;

    const int t = threadIdx.x, lane = t & 63, w = t >> 6;
    const int wr = w >> 2, wc = w & 3;
    const int l15 = lane & 15, lhi = lane >> 4;

    const u16* gpA[2]; const u16* gpB[2];
    int lofA[2], lofB[2];
#pragma unroll
    for (int it = 0; it < 2; ++it) {
        const int ci = it * 512 + t;
        const int row = ci >> 2, slot = ci & 3;
        const int gs = slot ^ rh(row);
        int ar = row0 + row; if (ar > M - 1) ar = M - 1;
        gpA[it] = A + (size_t)ar * K + (gs << 3);
        gpB[it] = B + (size_t)(col0 + row) * K + (gs << 3);
        lofA[it] = ci * 8;
        lofB[it] = 8192 + ci * 8;
    }

    const int ss = rh(l15);
    const unsigned lb0 = ldsa(lds);
    unsigned aof[8], bof[4];
#pragma unroll
    for (int i = 0; i < 8; ++i) {
        const int ar = wr * 128 + i * 16 + l15;
        aof[i] = (unsigned)((ar * 32 + ((lhi ^ ss) << 3)) * 2);
    }
#pragma unroll
    for (int n = 0; n < 4; ++n) {
        const int br = wc * 64 + n * 16 + l15;
        bof[n] = (unsigned)((8192 + br * 32 + ((lhi ^ ss) << 3)) * 2);
    }

    f32x4 acc[8][4] = {};
    const int NT = K >> 5;

#define SBAR0() __builtin_amdgcn_sched_barrier(0)
#define BARX()  do { SBAR0(); __builtin_amdgcn_s_barrier(); SBAR0(); } while (0)

#pragma unroll
    for (int p = 0; p < 3; ++p) {
        const size_t kp = (size_t)p << 5;
        u16* lb = lds + (p << 14);
        gload16(gpA[0] + kp, lb + lofA[0]); gload16(gpA[1] + kp, lb + lofA[1]);
        gload16(gpB[0] + kp, lb + lofB[0]); gload16(gpB[1] + kp, lb + lofB[1]);
    }
    asm volatile("s_waitcnt vmcnt(4)" ::: "memory");
    BARX();

    f16x8 al[4], ah[4], bb[4];
#pragma unroll
    for (int nf = 0; nf < 4; ++nf) bb[nf] = dsr128(lb0 + bof[nf]);
#pragma unroll
    for (int mf = 0; mf < 4; ++mf) al[mf] = dsr128(lb0 + aof[mf]);
    SBAR0();

    for (int tt = 0; tt < NT; ++tt) {
        const unsigned cb = lb0 + ((unsigned)(tt & 3) << 15);
        const unsigned nb = lb0 + ((unsigned)((tt + 1) & 3) << 15);
        u16* lsb = lds + (((tt + 3) & 3) << 14);
        const int tx = (tt + 3 < NT) ? tt + 3 : tt + 3 - NT;
        const size_t kn = (size_t)tx << 5;

        gload16(gpA[0] + kn, lsb + lofA[0]);
        gload16(gpA[1] + kn, lsb + lofA[1]);
#pragma unroll
        for (int mf = 0; mf < 4; ++mf) ah[mf] = dsr128(cb + aof[4 + mf]);
        SBAR0();
        asm volatile("s_waitcnt lgkmcnt(4)" ::: "memory");
        SBAR0();
        __builtin_amdgcn_s_setprio(1);
#pragma unroll
        for (int nf = 0; nf < 4; ++nf)
#pragma unroll
            for (int mf = 0; mf < 4; ++mf)
                acc[mf][nf] = MFMAH(al[mf], bb[nf], acc[mf][nf]);
        __builtin_amdgcn_s_setprio(0);
#pragma unroll
        for (int mf = 0; mf < 4; ++mf) al[mf] = dsr128(nb + aof[mf]);
        SBAR0();
        gload16(gpB[0] + kn, lsb + lofB[0]);
        gload16(gpB[1] + kn, lsb + lofB[1]);
        asm volatile("s_waitcnt lgkmcnt(4)" ::: "memory");
        SBAR0();
        __builtin_amdgcn_s_setprio(1);
#pragma unroll
        for (int nf = 0; nf < 4; ++nf)
#pragma unroll
            for (int mf = 0; mf < 4; ++mf)
                acc[4 + mf][nf] = MFMAH(ah[mf], bb[nf], acc[4 + mf][nf]);
        __builtin_amdgcn_s_setprio(0);
#pragma unroll
        for (int nf = 0; nf < 4; ++nf) bb[nf] = dsr128(nb + bof[nf]);
        SBAR0();
        asm volatile("s_waitcnt vmcnt(4)" ::: "memory");
        BARX();
    }
    asm volatile("s_waitcnt vmcnt(0) lgkmcnt(0)" ::: "memory");

#pragma unroll
    for (int nf = 0; nf < 4; ++nf) {
        const int col = col0 + wc * 64 + nf * 16 + l15;
        const float bs = bias[col];
#pragma unroll
        for (int mf = 0; mf < 8; ++mf) {
            const int row = row0 + wr * 128 + mf * 16 + (lhi << 2);
#pragma unroll
            for (int r = 0; r < 4; ++r) {
                if (row + r < M) {
                    const float v = acc[mf][nf][r] + bs;
                    if (OUTF32) ((float*)Cout)[(size_t)(row + r) * N + col] = v;
                    else        ((u16*)Cout)[(size_t)(row + r) * N + col] = f2h(v);
                }
            }
        }
    }
#undef SBAR0
#undef BARX
}

// ---------------------------------------------------------------------------
// Fused attention, fp16 in/out (unchanged, known-good). One block per
// (qtile=64,h,b), 4 waves x 16 q-rows. O written IN-PLACE over q.
// ---------------------------------------------------------------------------
#define ALDK 200
#define ALDP 104

__global__ void attn_fused(const u16* __restrict__ qbuf, const u16* __restrict__ kbuf,
                           const u16* __restrict__ vbuf, u16* __restrict__ obuf) {
    __shared__ u16 Ks[80 * ALDK];
    __shared__ u16 Pls[64 * ALDP];
    __shared__ u16 Vt[96 * ALDP];

    const int t = threadIdx.x, lane = t & 63, w = t >> 6;
    const int qt = blockIdx.x, h = blockIdx.y, b = blockIdx.z;
    const int l15 = lane & 15, lhi = lane >> 4;

    f16x8 qf[6];
    {
        const size_t qrow = (size_t)(b * 1024 + qt * 64 + w * 16 + l15);
        const u16* qp = qbuf + qrow * 1536 + h * 192 + (lhi << 3);
#pragma unroll
        for (int kt = 0; kt < 6; ++kt) qf[kt] = *(const f16x8*)(qp + kt * 32);
    }

    for (int c = t; c < 80 * 24; c += 256) {
        const int s = c / 24, d8 = (c - s * 24) << 3;
        s16x8 val = {};
        if (s < 77) val = *(const s16x8*)&kbuf[(size_t)(b * 77 + s) * 1536 + h * 192 + d8];
        *(s16x8*)&Ks[s * ALDK + d8] = val;
    }
    for (int c = t; c < 96 * 12; c += 256) {
        const int s = c % 96, d8 = (c / 96) << 3;
        s16x8 val = {};
        if (s < 77) val = *(const s16x8*)&vbuf[(size_t)(b * 77 + s) * 1536 + h * 192 + d8];
#pragma unroll
        for (int j = 0; j < 8; ++j) Vt[(d8 + j) * ALDP + s] = (u16)val[j];
    }
    {
        const int row = w * 16 + l15;
        s16x4 zz = {0, 0, 0, 0};
        *(s16x4*)&Pls[row * ALDP + 80 + (lhi << 2)] = zz;
    }
    __syncthreads();

    f32x4 sacc[5] = {};
#pragma unroll
    for (int kt = 0; kt < 6; ++kt) {
#pragma unroll
        for (int nf = 0; nf < 5; ++nf) {
            f16x8 kf = *(const f16x8*)&Ks[(nf * 16 + l15) * ALDK + kt * 32 + (lhi << 3)];
            sacc[nf] = MFMAH(qf[kt], kf, sacc[nf]);
        }
    }

    float rps[4];
    const float scale = 0.07216878364870323f;
#pragma unroll
    for (int r = 0; r < 4; ++r) {
        float m = -1e30f;
#pragma unroll
        for (int nf = 0; nf < 5; ++nf) {
            const int c = nf * 16 + l15;
            const float sv = sacc[nf][r] * scale;
            if (c < 77) m = fmaxf(m, sv);
        }
#pragma unroll
        for (int off = 1; off < 16; off <<= 1) m = fmaxf(m, __shfl_xor(m, off));
        float sum = 0.f;
#pragma unroll
        for (int nf = 0; nf < 5; ++nf) {
            const int c = nf * 16 + l15;
            const float p = (c < 77) ? __expf(sacc[nf][r] * scale - m) : 0.f;
            sacc[nf][r] = p;
            sum += p;
        }
#pragma unroll
        for (int off = 1; off < 16; off <<= 1) sum += __shfl_xor(sum, off);
        rps[r] = 1.0f / sum;
    }

#pragma unroll
    for (int r = 0; r < 4; ++r)
#pragma unroll
        for (int nf = 0; nf < 5; ++nf)
            Pls[(w * 16 + (lhi << 2) + r) * ALDP + nf * 16 + l15] = f2h(sacc[nf][r]);
    __syncthreads();

    f16x8 pa[3];
#pragma unroll
    for (int kt = 0; kt < 3; ++kt)
        pa[kt] = *(const f16x8*)&Pls[(w * 16 + l15) * ALDP + kt * 32 + (lhi << 3)];

    const size_t orow = (size_t)(b * 1024 + qt * 64 + w * 16 + (lhi << 2));

    {
        f32x4 oacc[6] = {};
#pragma unroll
        for (int kt = 0; kt < 3; ++kt)
#pragma unroll
            for (int nf = 0; nf < 6; ++nf) {
                f16x8 vf = *(const f16x8*)&Vt[(nf * 16 + l15) * ALDP + kt * 32 + (lhi << 3)];
                oacc[nf] = MFMAH(pa[kt], vf, oacc[nf]);
            }
#pragma unroll
        for (int nf = 0; nf < 6; ++nf) {
            const int col = h * 192 + nf * 16 + l15;
#pragma unroll
            for (int r = 0; r < 4; ++r)
                obuf[(orow + r) * 1536 + col] = f2h(oacc[nf][r] * rps[r]);
        }
    }
    __syncthreads();
    for (int c = t; c < 96 * 12; c += 256) {
        const int s = c % 96, d8 = (c / 96) << 3;
        s16x8 val = {};
        if (s < 77) val = *(const s16x8*)&vbuf[(size_t)(b * 77 + s) * 1536 + h * 192 + 96 + d8];
#pragma unroll
        for (int j = 0; j < 8; ++j) Vt[(d8 + j) * ALDP + s] = (u16)val[j];
    }
    __syncthreads();
    {
        f32x4 oacc[6] = {};
#pragma unroll
        for (int kt = 0; kt < 3; ++kt)
#pragma unroll
            for (int nf = 0; nf < 6; ++nf) {
                f16x8 vf = *(const f16x8*)&Vt[(nf * 16 + l15) * ALDP + kt * 32 + (lhi << 3)];
                oacc[nf] = MFMAH(pa[kt], vf, oacc[nf]);
            }
#pragma unroll
        for (int nf = 0; nf < 6; ++nf) {
            const int col = h * 192 + 96 + nf * 16 + l15;
#pragma unroll
            for (int r = 0; r < 4; ++r)
                obuf[(orow + r) * 1536 + col] = f2h(oacc[nf][r] * rps[r]);
        }
    }
}

// ---------------------------------------------------------------------------
extern "C" void kernel_launch(void* const* d_in, const int* in_sizes, int n_in,
                              void* d_out, int out_size, void* d_ws, size_t ws_size,
                              hipStream_t stream) {
    const float* img  = (const float*)d_in[0];
    const float* text = (const float*)d_in[1];
    const float* Wq   = (const float*)d_in[2];
    const float* bq   = (const float*)d_in[3];
    const float* Wk   = (const float*)d_in[4];
    const float* bk   = (const float*)d_in[5];
    const float* Wv   = (const float*)d_in[6];
    const float* bv   = (const float*)d_in[7];
    const float* Wo   = (const float*)d_in[8];
    const float* bo   = (const float*)d_in[9];

    const size_t imgN = (size_t)32768 * 1536;
    const size_t txtN = (size_t)2464 * 1536;
    const size_t wN   = (size_t)1536 * 1536;

    // ws layout (~130 MB of fp16; img_h eliminated)
    u16* qb    = (u16*)d_ws;        // [imgN]  q fp16, O overwrites in-place
    u16* txt_h = qb + imgN;         // [txtN]
    u16* Wq_h  = txt_h + txtN;
    u16* Wk_h  = Wq_h + wN;
    u16* Wv_h  = Wk_h + wN;
    u16* Wo_h  = Wv_h + wN;
    u16* kb    = Wo_h + wN;         // [txtN]
    u16* vb    = kb + txtN;         // [txtN]

    // 1) convert text + weights (img converted inside qkv_gemm)
    Conv5Args ca;
    ca.x[0] = text; ca.h[0] = txt_h; ca.n8[0] = (int)(txtN / 8);
    ca.x[1] = Wq;   ca.h[1] = Wq_h;  ca.n8[1] = (int)(wN / 8);
    ca.x[2] = Wk;   ca.h[2] = Wk_h;  ca.n8[2] = (int)(wN / 8);
    ca.x[3] = Wv;   ca.h[3] = Wv_h;  ca.n8[3] = (int)(wN / 8);
    ca.x[4] = Wo;   ca.h[4] = Wo_h;  ca.n8[4] = (int)(wN / 8);
    hipLaunchKernelGGL(conv_h5, dim3((unsigned)((txtN / 8 + 255) / 256), 5),
                       dim3(256), 0, stream, ca);

    // 2) fused q/k/v projections: z=0 q (768 blocks), z=1 k, z=2 v (60 each)
    hipLaunchKernelGGL(qkv_gemm, dim3(768, 1, 3), dim3(512), 0, stream,
                       img, txt_h, Wq_h, Wk_h, Wv_h, bq, bk, bv, qb, kb, vb);

    // 3) attention (O in-place over q)
    hipLaunchKernelGGL(attn_fused, dim3(16, 8, 32), dim3(256), 0, stream,
                       qb, kb, vb, qb);

    // 4) output projection (fp32 out), R12 pipelined kernel
    hipLaunchKernelGGL((gemm_h_nt<1>), dim3(768), dim3(512), 0, stream,
                       qb, Wo_h, bo, d_out, Wo_h, bo, d_out,
                       32768, 1536, 1536, 6);
}